// Round 11
// baseline (429.677 us; speedup 1.0000x reference)
//
#include <hip/hip_runtime.h>
#include <hip/hip_cooperative_groups.h>

namespace cg = cooperative_groups;

typedef unsigned short u16;
typedef unsigned int u32;
typedef __attribute__((ext_vector_type(8))) short bfrag;     // 8 bf16
typedef __attribute__((ext_vector_type(4))) float ffrag;     // 4 fp32 acc
typedef __attribute__((ext_vector_type(16))) float ffrag16;  // 16 fp32 acc (32x32)

__device__ __forceinline__ float lrelu(float x) { return x >= 0.f ? x : 0.01f * x; }
__device__ __forceinline__ float eluf(float x)  { return x > 0.f ? x : expm1f(x); }
__device__ __forceinline__ u16 f2bf(float f) {            // RNE (wprep only)
    u32 x = __float_as_uint(f);
    return (u16)((x + 0x7fffu + ((x >> 16) & 1u)) >> 16);
}
__device__ __forceinline__ u16 f2bt(float f) {            // truncate (internal)
    return (u16)(__float_as_uint(f) >> 16);
}
__device__ __forceinline__ float bf2f(u16 u) {
    return __uint_as_float(((u32)u) << 16);
}

// sparsemax over 16 elements (Martins & Astudillo), exact ksup-count semantics
__device__ void sparsemax16(const float* z, float* out) {
    float zs[16];
    for (int i = 0; i < 16; ++i) zs[i] = z[i];
    for (int i = 1; i < 16; ++i) {
        float key = zs[i]; int j = i - 1;
        while (j >= 0 && zs[j] < key) { zs[j + 1] = zs[j]; --j; }
        zs[j + 1] = key;
    }
    float cum[16];
    cum[0] = zs[0];
    for (int i = 1; i < 16; ++i) cum[i] = cum[i - 1] + zs[i];
    int ksup = 0;
    for (int k = 1; k <= 16; ++k)
        if (1.0f + (float)k * zs[k - 1] > cum[k - 1]) ksup++;
    if (ksup < 1) ksup = 1;
    float tau = (cum[ksup - 1] - 1.0f) / (float)ksup;
    for (int i = 0; i < 16; ++i) out[i] = fmaxf(z[i] - tau, 0.0f);
}

// ---- weight pre-pack into B-fragment order (bf16), 4 elems/thread ----------
__global__ __launch_bounds__(256) void k_wprep(
    const float* __restrict__ w2, const float* __restrict__ w3,
    const float* __restrict__ Wq, const float* __restrict__ Wk,
    const float* __restrict__ Wv,
    u16* __restrict__ wpk2, u16* __restrict__ wpk3, u16* __restrict__ wqkv)
{
    int i0 = (blockIdx.x * 256 + threadIdx.x) * 4;
    for (int t = 0; t < 4; ++t) {
        int i = i0 + t;
        if (i < 131072) {
            int j = i & 7, L = (i >> 3) & 63, kc = (i >> 9) & 7, nt = (i >> 12) & 3, f = i >> 14;
            int co = nt * 16 + (L & 15);
            int ci = ((L >> 4) << 3) + j;
            wpk2[i] = f2bf(w2[(((size_t)f * 64 + co) * 32 + ci) * 8 + kc]);
        } else if (i < 131072 + 524288) {
            int i2 = i - 131072;
            int j = i2 & 7, L = (i2 >> 3) & 63, kt = (i2 >> 9) & 31, nt = (i2 >> 14) & 3, f = i2 >> 16;
            int co = nt * 32 + (L & 31);
            int ci = (kt & 3) * 16 + ((L >> 5) << 3) + j;
            int tap = kt >> 2;
            wpk3[i2] = f2bf(w3[(((size_t)f * 128 + co) * 64 + ci) * 8 + tap]);
        } else if (i < 131072 + 524288 + 49152) {
            int j2 = i - 655360;
            int proj = j2 >> 14, idx = j2 & 16383;
            int jj = idx & 7, L = (idx >> 3) & 63, kc = (idx >> 9) & 3, nt = idx >> 11;
            int n = nt * 16 + (L & 15);
            int k = kc * 32 + ((L >> 4) << 3) + jj;
            const float* W = proj == 0 ? Wq : (proj == 1 ? Wk : Wv);
            wqkv[j2] = f2bf(W[k * 128 + n]);
        }
    }
}

// ===== fused CNN (both passes): conv1 fp32 -> conv2/conv3 bf16 MFMA ==========
// R10-exact (94 us, FETCH 7.4MB, conflicts 2.6M). Unchanged this round.
#define S1T_STRIDE 40
#define S2T_STRIDE 72
#define RB2_STRIDE 68
#define RB3_STRIDE 140
#define RB_OFF 6336
#define SMEM_U16 (RB_OFF + 67 * RB3_STRIDE)

__global__ __launch_bounds__(256, 3) void k_cnn(
    const float* __restrict__ xs, const float* __restrict__ xt,
    const float* __restrict__ w1, const float* __restrict__ g1, const float* __restrict__ b1,
    const float* __restrict__ m1, const float* __restrict__ v1,
    const float* __restrict__ g2, const float* __restrict__ b2,
    const float* __restrict__ m2, const float* __restrict__ v2,
    const float* __restrict__ g3, const float* __restrict__ b3,
    const float* __restrict__ m3, const float* __restrict__ v3,
    const u16* __restrict__ wpk2, const u16* __restrict__ wpk3,
    float* __restrict__ rep)
{
    __shared__ __align__(16) u16 smem[SMEM_U16];
    float* xin = (float*)(smem + RB_OFF);      // 264 floats (region B head)

    int tid = threadIdx.x, blk = blockIdx.x;
    int pass = blk >> 11, f = (blk >> 8) & 7, n = blk & 255;
    int bb = n >> 4, ss = n & 15;
    int lane = tid & 63, w = tid >> 6;
    const float* x = pass ? xt : xs;
    float* rep_p = rep + (size_t)pass * 262144;

    {
        u32* z = (u32*)smem;
        for (int i = tid; i < 80; i += 256) z[i] = 0;          // s1T rows 0..3
        for (int i = tid; i < 360; i += 256) z[2660 + i] = 0;  // s1T rows 133..150
        if (tid < 4) { xin[tid] = 0.f; xin[260 + tid] = 0.f; }
        const float* xr = x + (((size_t)bb * 8 + f) * 16 + ss) * 256;
        for (int i = tid; i < 256; i += 256) xin[i + 4] = xr[i];
    }
    __syncthreads();

    // ---- conv1 fp32 (1->32, 256 -> conv 257 -> pool 129), ushort4 stores ----
    if (tid < 208) {
        int cc = tid & 7, jc = tid >> 3;
        int co0 = cc * 4, j0 = jc * 5;
        float wr[4][8];
        for (int c = 0; c < 4; ++c) {
            const float4* q = reinterpret_cast<const float4*>(w1 + ((size_t)f * 32 + co0 + c) * 8);
            float4 a = q[0], bq = q[1];
            wr[c][0] = a.x; wr[c][1] = a.y; wr[c][2] = a.z; wr[c][3] = a.w;
            wr[c][4] = bq.x; wr[c][5] = bq.y; wr[c][6] = bq.z; wr[c][7] = bq.w;
        }
        int px[10];
        for (int i = 0; i < 10; ++i) {
            int p = 2 * j0 - 1 + i;
            px[i] = p < 0 ? 0 : (p > 256 ? 256 : p);
        }
        float acc[4][10];
        for (int c = 0; c < 4; ++c) for (int i = 0; i < 10; ++i) acc[c][i] = 0.f;
        for (int k = 0; k < 8; ++k) {
            float xv[10];
            for (int i = 0; i < 10; ++i) xv[i] = xin[px[i] + k];
            for (int c = 0; c < 4; ++c)
                for (int i = 0; i < 10; ++i) acc[c][i] += wr[c][k] * xv[i];
        }
        float scv[4], shv[4];
        for (int c = 0; c < 4; ++c) {
            int co = co0 + c;
            scv[c] = g1[f * 32 + co] * rsqrtf(v1[f * 32 + co] + 1e-5f);
            shv[c] = b1[f * 32 + co] - m1[f * 32 + co] * scv[c];
        }
        for (int jj = 0; jj < 5; ++jj) {
            int j = j0 + jj;
            if (j < 129) {
                ushort4 pk;
                {
                    float a0 = fmaxf(acc[0][2*jj] * scv[0] + shv[0], 0.f);
                    float a1 = fmaxf(acc[0][2*jj+1] * scv[0] + shv[0], 0.f);
                    pk.x = f2bt(fmaxf(a0, a1));
                }
                {
                    float a0 = fmaxf(acc[1][2*jj] * scv[1] + shv[1], 0.f);
                    float a1 = fmaxf(acc[1][2*jj+1] * scv[1] + shv[1], 0.f);
                    pk.y = f2bt(fmaxf(a0, a1));
                }
                {
                    float a0 = fmaxf(acc[2][2*jj] * scv[2] + shv[2], 0.f);
                    float a1 = fmaxf(acc[2][2*jj+1] * scv[2] + shv[2], 0.f);
                    pk.z = f2bt(fmaxf(a0, a1));
                }
                {
                    float a0 = fmaxf(acc[3][2*jj] * scv[3] + shv[3], 0.f);
                    float a1 = fmaxf(acc[3][2*jj+1] * scv[3] + shv[3], 0.f);
                    pk.w = f2bt(fmaxf(a0, a1));
                }
                *reinterpret_cast<ushort4*>(&smem[(j + 4) * S1T_STRIDE + co0]) = pk;
            }
        }
    }
    __syncthreads();

    // ---- conv2 MFMA (M=130, N=64, K=256) -> RB2 raw ----
    {
        bfrag B2[2][8];
        {
            const bfrag* gB = reinterpret_cast<const bfrag*>(wpk2);
            int wN = w & 1;
#pragma unroll
            for (int t = 0; t < 2; ++t)
#pragma unroll
                for (int kc = 0; kc < 8; ++kc)
                    B2[t][kc] = gB[(((size_t)f * 4 + (wN * 2 + t)) * 8 + kc) * 64 + lane];
        }
        int wM = w >> 1, wN = w & 1;
        float sc2[2], sh2[2];
        int co2[2];
#pragma unroll
        for (int t = 0; t < 2; ++t) {
            int co = (wN * 2 + t) * 16 + (lane & 15);
            co2[t] = co;
            sc2[t] = g2[f * 64 + co] * rsqrtf(v2[f * 64 + co] + 1e-5f);
            sh2[t] = b2[f * 64 + co] - m2[f * 64 + co] * sc2[t];
        }
        int arow = lane & 15, ci0 = (lane >> 4) << 3;
        int mtlo = wM ? 5 : 0, mthi = wM ? 9 : 5;
        for (int mt = mtlo; mt < mthi; ++mt) {
            ffrag C0 = {0.f, 0.f, 0.f, 0.f}, C1 = {0.f, 0.f, 0.f, 0.f};
            int rb = mt * 16 + arow;
#pragma unroll
            for (int kc = 0; kc < 8; ++kc) {
                bfrag A = *reinterpret_cast<const bfrag*>(&smem[(rb + kc) * S1T_STRIDE + ci0]);
                C0 = __builtin_amdgcn_mfma_f32_16x16x32_bf16(A, B2[0][kc], C0, 0, 0, 0);
                C1 = __builtin_amdgcn_mfma_f32_16x16x32_bf16(A, B2[1][kc], C1, 0, 0, 0);
            }
            int p0 = mt * 16 + ((lane >> 4) << 2);
#pragma unroll
            for (int r = 0; r < 4; ++r) {
                int p = p0 + r;
                if (p < 130) {
                    smem[RB_OFF + p * RB2_STRIDE + co2[0]] = f2bt(fmaxf(C0[r] * sc2[0] + sh2[0], 0.f));
                    smem[RB_OFF + p * RB2_STRIDE + co2[1]] = f2bt(fmaxf(C1[r] * sc2[1] + sh2[1], 0.f));
                }
            }
        }
    }
    __syncthreads();

    // ---- pool conv2 -> s2T (region A) + zero pad rows, u32-vectorized ----
    {
        u32* z = (u32*)smem;
        for (int i = tid; i < 144; i += 256) z[i] = 0;
        for (int i = tid; i < 612; i += 256) z[2520 + i] = 0;
    }
    {
        const u32* rb2 = reinterpret_cast<const u32*>(smem + RB_OFF);  // stride 34
        u32* s2 = reinterpret_cast<u32*>(smem);                        // stride 36
        for (int e = tid; e < 66 * 32; e += 256) {
            int j = e >> 5, c2 = e & 31;
            u32 v;
            if (j == 0) {
                v = rb2[c2];
            } else if (j == 65) {
                v = rb2[129 * 34 + c2];
            } else {
                u32 a = rb2[(2 * j - 1) * 34 + c2];
                u32 b = rb2[(2 * j) * 34 + c2];
                float a0 = bf2f((u16)a), a1 = bf2f((u16)(a >> 16));
                float b0 = bf2f((u16)b), b1 = bf2f((u16)(b >> 16));
                u16 m0 = a0 > b0 ? (u16)a : (u16)b;
                u16 m1 = a1 > b1 ? (u16)(a >> 16) : (u16)(b >> 16);
                v = (u32)m0 | ((u32)m1 << 16);
            }
            s2[(j + 4) * 36 + c2] = v;
        }
    }
    __syncthreads();

    // ---- conv3 MFMA 32x32x16, kt-outer: 1 B-load + 3 A-reads + 3 MFMA/step --
    {
        int am = lane & 31, hk = (lane >> 5) << 3;
        const bfrag* gB3 = reinterpret_cast<const bfrag*>(wpk3);
        size_t bbase = (((size_t)f * 4 + w) * 32) * 64 + lane;
        ffrag16 C0 = {0.f,0.f,0.f,0.f,0.f,0.f,0.f,0.f,0.f,0.f,0.f,0.f,0.f,0.f,0.f,0.f};
        ffrag16 C1 = {0.f,0.f,0.f,0.f,0.f,0.f,0.f,0.f,0.f,0.f,0.f,0.f,0.f,0.f,0.f,0.f};
        ffrag16 C2 = {0.f,0.f,0.f,0.f,0.f,0.f,0.f,0.f,0.f,0.f,0.f,0.f,0.f,0.f,0.f,0.f};
#pragma unroll 4
        for (int kt = 0; kt < 32; ++kt) {
            int row0 = am + (kt >> 2);
            int ci0 = (kt & 3) * 16 + hk;
            bfrag B = gB3[bbase + (size_t)kt * 64];
            bfrag A0 = *reinterpret_cast<const bfrag*>(&smem[row0 * S2T_STRIDE + ci0]);
            bfrag A1 = *reinterpret_cast<const bfrag*>(&smem[(row0 + 32) * S2T_STRIDE + ci0]);
            bfrag A2 = *reinterpret_cast<const bfrag*>(&smem[(row0 + 64) * S2T_STRIDE + ci0]);
            C0 = __builtin_amdgcn_mfma_f32_32x32x16_bf16(A0, B, C0, 0, 0, 0);
            C1 = __builtin_amdgcn_mfma_f32_32x32x16_bf16(A1, B, C1, 0, 0, 0);
            C2 = __builtin_amdgcn_mfma_f32_32x32x16_bf16(A2, B, C2, 0, 0, 0);
        }
        int ncol = w * 32 + am;
        float sc = g3[f * 128 + ncol] * rsqrtf(v3[f * 128 + ncol] + 1e-5f);
        float sh = b3[f * 128 + ncol] - m3[f * 128 + ncol] * sc;
        int prow_off = (lane >> 5) << 2;
#pragma unroll
        for (int reg = 0; reg < 16; ++reg) {
            int pr = (reg & 3) + 8 * (reg >> 2) + prow_off;
            smem[RB_OFF + pr * RB3_STRIDE + ncol] = f2bt(fmaxf(C0[reg] * sc + sh, 0.f));
            smem[RB_OFF + (32 + pr) * RB3_STRIDE + ncol] = f2bt(fmaxf(C1[reg] * sc + sh, 0.f));
            int p2 = 64 + pr;
            if (p2 < 67)
                smem[RB_OFF + p2 * RB3_STRIDE + ncol] = f2bt(fmaxf(C2[reg] * sc + sh, 0.f));
        }
    }
    __syncthreads();

    // ---- pool conv3 + mean -> rep ----
    if (tid < 128) {
        int co = tid;
        float sum = bf2f(smem[RB_OFF + 0 * RB3_STRIDE + co]);
        for (int j = 1; j < 34; ++j) {
            float a0 = bf2f(smem[RB_OFF + (2 * j - 1) * RB3_STRIDE + co]);
            float a1 = bf2f(smem[RB_OFF + (2 * j) * RB3_STRIDE + co]);
            sum += fmaxf(a0, a1);
        }
        rep_p[(((size_t)f * 256) + n) * 128 + co] = sum * (1.0f / 34.0f);
    }
}

// ===== fused post-CNN chain (cooperative): attn1 -> attn2 -> head1 -> tail ==
// One 256-block kernel, 3 grid syncs. Phase bodies are the verified k_attn1/
// k_attn2/k_head1/k_tail bodies, re-aliased onto one LDS arena (max 66.1 KB,
// attn2's repL). 2 blocks/CU co-residency >= 256 blocks -> cooperative OK.
__global__ __launch_bounds__(256) void k_post(
    const float* __restrict__ rep, const u16* __restrict__ wqkv,
    const float* __restrict__ bq, const float* __restrict__ bk,
    const float* __restrict__ bv,
    float* __restrict__ Zn, float* __restrict__ rninv,
    float* __restrict__ ia, float* __restrict__ ib,
    const float* __restrict__ c1g, const float* __restrict__ c1b,
    const float* __restrict__ c1m, const float* __restrict__ c1v,
    float* __restrict__ featbn,
    const float* __restrict__ W1, const float* __restrict__ b1,
    const float* __restrict__ c2g, const float* __restrict__ c2b,
    const float* __restrict__ c2m, const float* __restrict__ c2v,
    float* __restrict__ h2ws,
    const float* __restrict__ W2, const float* __restrict__ b2,
    const int* __restrict__ sy, float* __restrict__ dout)
{
    cg::grid_group grid = cg::this_grid();
    __shared__ __align__(16) unsigned char smraw[67712];
    int tid = threadIdx.x, blk = blockIdx.x;
    int lane = tid & 63, w = tid >> 6;

    // ---------------- Phase A: attn1, blk = (pass,f,b) ----------------
    {
        u16* repbf = reinterpret_cast<u16*>(smraw);                 // [16*136]
        float* KmL = reinterpret_cast<float*>(smraw + 4352);        // [128]
        float* ZL = reinterpret_cast<float*>(smraw + 4864);         // [128]
        float* awL = reinterpret_cast<float*>(smraw + 5376);        // [16]
        float* scoresL = reinterpret_cast<float*>(smraw + 5440);    // [16]
        float* r2L = reinterpret_cast<float*>(smraw + 5504);        // [16]
        float* spart = reinterpret_cast<float*>(smraw + 5568);      // [4][4][4]
        float* redL = reinterpret_cast<float*>(smraw + 5824);       // [4]

        int pass = blk >> 7, f = (blk >> 4) & 7, b = blk & 15;
        const float* rp = rep + (size_t)pass * 262144 + ((size_t)f * 256 + b * 16) * 128;
        float* Zn_p = Zn + (size_t)pass * 16384;
        float* rninv_p = rninv + (size_t)pass * 2048;
        float* iaw_p = ia + (size_t)pass * 2048;

        {
            int s = tid >> 4, i = tid & 15, h0 = i * 8;
            const float4* q4 = reinterpret_cast<const float4*>(rp + s * 128 + h0);
            float4 a = q4[0], c = q4[1];
            float p2 = a.x*a.x + a.y*a.y + a.z*a.z + a.w*a.w
                     + c.x*c.x + c.y*c.y + c.z*c.z + c.w*c.w;
            bfrag pk;
            pk[0] = (short)f2bt(a.x); pk[1] = (short)f2bt(a.y);
            pk[2] = (short)f2bt(a.z); pk[3] = (short)f2bt(a.w);
            pk[4] = (short)f2bt(c.x); pk[5] = (short)f2bt(c.y);
            pk[6] = (short)f2bt(c.z); pk[7] = (short)f2bt(c.w);
            *reinterpret_cast<bfrag*>(&repbf[s * 136 + h0]) = pk;
            p2 += __shfl_xor(p2, 1); p2 += __shfl_xor(p2, 2);
            p2 += __shfl_xor(p2, 4); p2 += __shfl_xor(p2, 8);
            if (i == 0) r2L[s] = p2;
        }
        __syncthreads();

        int arow = lane & 15, q = lane >> 4;
        bfrag A[4];
        for (int kc = 0; kc < 4; ++kc)
            A[kc] = *reinterpret_cast<const bfrag*>(&repbf[arow * 136 + kc * 32 + q * 8]);

        float qv[2][4], vvv[2][4];
        int colv[2];
        const bfrag* BB = reinterpret_cast<const bfrag*>(wqkv);
        for (int t = 0; t < 2; ++t) {
            int nt = w * 2 + t;
            ffrag cq = {0.f,0.f,0.f,0.f}, ck = {0.f,0.f,0.f,0.f}, cv = {0.f,0.f,0.f,0.f};
            for (int kc = 0; kc < 4; ++kc) {
                int fi = (nt * 4 + kc) * 64 + lane;
                bfrag Bq = BB[fi];
                bfrag Bk = BB[2048 + fi];
                bfrag Bv = BB[4096 + fi];
                cq = __builtin_amdgcn_mfma_f32_16x16x32_bf16(A[kc], Bq, cq, 0, 0, 0);
                ck = __builtin_amdgcn_mfma_f32_16x16x32_bf16(A[kc], Bk, ck, 0, 0, 0);
                cv = __builtin_amdgcn_mfma_f32_16x16x32_bf16(A[kc], Bv, cv, 0, 0, 0);
            }
            int col = nt * 16 + arow;
            colv[t] = col;
            float bqc = bq[col], bkc = bk[col], bvc = bv[col];
            float kpt = 0.f;
            for (int r = 0; r < 4; ++r) {
                qv[t][r] = eluf(cq[r] + bqc);
                vvv[t][r] = lrelu(cv[r] + bvc);
                kpt += lrelu(ck[r] + bkc);
            }
            kpt += __shfl_xor(kpt, 16);
            kpt += __shfl_xor(kpt, 32);
            if (q == 0) KmL[col] = kpt * (1.f / 16.f);
        }
        __syncthreads();

        {
            float km0 = KmL[colv[0]], km1 = KmL[colv[1]];
            float ps[4];
            for (int r = 0; r < 4; ++r) {
                float v = qv[0][r] * km0 + qv[1][r] * km1;
                v += __shfl_xor(v, 1); v += __shfl_xor(v, 2);
                v += __shfl_xor(v, 4); v += __shfl_xor(v, 8);
                ps[r] = v;
            }
            if (arow == 0)
                for (int r = 0; r < 4; ++r) spart[((w << 2) + q) * 4 + r] = ps[r];
        }
        __syncthreads();
        if (tid < 16) {
            int qq = tid >> 2, rr = tid & 3;
            float sc = spart[(0 + qq) * 4 + rr] + spart[(4 + qq) * 4 + rr]
                     + spart[(8 + qq) * 4 + rr] + spart[(12 + qq) * 4 + rr];
            scoresL[tid] = sc * 0.08838834764831845f;   // 1/sqrt(128)
            rninv_p[f * 256 + b * 16 + tid] = 1.f / fmaxf(sqrtf(r2L[tid]), 1e-12f);
        }
        __syncthreads();
        if (tid == 0) sparsemax16(scoresL, awL);
        __syncthreads();
        if (tid < 16) iaw_p[f * 256 + b * 16 + tid] = awL[tid];

        for (int t = 0; t < 2; ++t) {
            float zp = 0.f;
            for (int r = 0; r < 4; ++r) zp += awL[q * 4 + r] * vvv[t][r];
            zp += __shfl_xor(zp, 16);
            zp += __shfl_xor(zp, 32);
            if (q == 0) ZL[colv[t]] = zp;
        }
        __syncthreads();
        if (tid < 128) {
            float z = ZL[tid];
            float v = z * z;
            v += __shfl_xor(v, 1); v += __shfl_xor(v, 2); v += __shfl_xor(v, 4);
            v += __shfl_xor(v, 8); v += __shfl_xor(v, 16); v += __shfl_xor(v, 32);
            if (lane == 0) redL[w] = v;
        }
        __syncthreads();
        if (tid == 0) redL[2] = 1.f / fmaxf(sqrtf(redL[0] + redL[1]), 1e-12f);
        __syncthreads();
        if (tid < 128)
            Zn_p[((size_t)f * 16 + b) * 128 + tid] = ZL[tid] * redL[2];
    }
    grid.sync();

    // ---------------- Phase B: attn2, blk = (pass,b,i) ----------------
    {
        float* repL = reinterpret_cast<float*>(smraw);              // [16384]
        float* ZiL = reinterpret_cast<float*>(smraw + 65536);       // [128]
        float* scores = reinterpret_cast<float*>(smraw + 66048);    // [128]
        float* UL = reinterpret_cast<float*>(smraw + 66560);        // [128]
        float* awLf = reinterpret_cast<float*>(smraw + 67072);      // [8][16]
        float* redL = reinterpret_cast<float*>(smraw + 67584);      // [2]

        int pass = blk >> 7, b = (blk >> 3) & 15, i = blk & 7;
        const float* rep_p = rep + (size_t)pass * 262144;

        for (int f = 0; f < 8; ++f) {
            const float4* src = reinterpret_cast<const float4*>(
                rep_p + ((size_t)f * 256 + b * 16) * 128);
            float4* dst = reinterpret_cast<float4*>(repL + f * 2048);
            for (int t = tid; t < 512; t += 256) dst[t] = src[t];
        }
        if (tid < 128) ZiL[tid] = Zn[(size_t)pass * 16384 + ((size_t)i * 16 + b) * 128 + tid];
        __syncthreads();

        if (tid < 128) {
            int f = tid >> 4, s = tid & 15;
            const float* rr = repL + tid * 128;
            float a = 0.f;
            for (int h = 0; h < 128; ++h) a += ZiL[h] * rr[h];
            scores[tid] = a * rninv[(size_t)pass * 2048 + f * 256 + b * 16 + s];
        }
        __syncthreads();
        if (tid < 8) {
            float aw[16];
            sparsemax16(&scores[tid * 16], aw);
            for (int s = 0; s < 16; ++s) awLf[tid * 16 + s] = aw[s];
        }
        __syncthreads();
        if (tid < 128) {
            int f = tid >> 4, s = tid & 15;
            ib[(size_t)pass * 16384 + (((size_t)i * 8 + f) * 16 + b) * 16 + s] = awLf[f * 16 + s];
        }
        if (pass == 0) {
            if (tid < 128) {
                int h = tid;
                float u = 0.f;
                for (int f = 0; f < 8; ++f) {
                    const float* rr = repL + f * 2048 + h;
                    const float* aa = awLf + f * 16;
                    for (int s = 0; s < 16; ++s) u += aa[s] * rr[s * 128];
                }
                UL[h] = u * 0.125f;
            }
            __syncthreads();
            if (tid < 128) {
                float v = ZiL[tid] * ZiL[tid] + UL[tid] * UL[tid];
                v += __shfl_xor(v, 1); v += __shfl_xor(v, 2); v += __shfl_xor(v, 4);
                v += __shfl_xor(v, 8); v += __shfl_xor(v, 16); v += __shfl_xor(v, 32);
                if (lane == 0) redL[w] = v;
            }
            __syncthreads();
            {
                float inv = 1.f / fmaxf(sqrtf(redL[0] + redL[1]), 1e-12f);
                int d = tid;
                int e = i * 256 + d;
                float val = (d < 128 ? ZiL[d] : UL[d - 128]) * inv;
                float scv = c1g[e] * rsqrtf(c1v[e] + 1e-5f);
                featbn[b * 2048 + e] = (val - c1m[e]) * scv + c1b[e];
            }
        }
    }
    grid.sync();

    // ---------------- Phase C: head1, blk = (b,cc) ----------------
    {
        float* featL = reinterpret_cast<float*>(smraw);             // [2048]
        float* part = reinterpret_cast<float*>(smraw + 8192);       // [32][32]

        int b = blk >> 4, cc = blk & 15;
        {
            const float4* src = reinterpret_cast<const float4*>(featbn + b * 2048);
            float4* dst = reinterpret_cast<float4*>(featL);
            for (int i = tid; i < 512; i += 256) dst[i] = src[i];
        }
        __syncthreads();
        int ks = tid >> 3, cg2 = tid & 7;
        int col0 = cc * 32 + cg2 * 4;
        float4 acc = {0.f, 0.f, 0.f, 0.f};
        const float* fl = featL + ks * 64;
        for (int c = 0; c < 64; ++c) {
            int k = ks * 64 + c;
            float4 wv = *reinterpret_cast<const float4*>(W1 + (size_t)k * 512 + col0);
            float fv = fl[c];
            acc.x += fv * wv.x; acc.y += fv * wv.y;
            acc.z += fv * wv.z; acc.w += fv * wv.w;
        }
        part[ks * 32 + cg2 * 4 + 0] = acc.x;
        part[ks * 32 + cg2 * 4 + 1] = acc.y;
        part[ks * 32 + cg2 * 4 + 2] = acc.z;
        part[ks * 32 + cg2 * 4 + 3] = acc.w;
        __syncthreads();
        if (tid < 32) {
            int colw = cc * 32 + tid;
            float s = b1[colw];
            for (int k2 = 0; k2 < 32; ++k2) s += part[k2 * 32 + tid];
            float scv = c2g[colw] * rsqrtf(c2v[colw] + 1e-5f);
            float val = (s - c2m[colw]) * scv + c2b[colw];
            h2ws[b * 512 + colw] = lrelu(val);
        }
    }
    grid.sync();

    // ---------------- Phase D: tail, block 0 only ----------------
    if (blk == 0) {
        float* h2L = reinterpret_cast<float*>(smraw);               // [8192]
        float* lgL = reinterpret_cast<float*>(smraw + 32768);       // [160]
        float* ypL = reinterpret_cast<float*>(smraw + 33408);       // [160]
        float* sA = reinterpret_cast<float*>(smraw + 34048);        // [8]
        float* sB = reinterpret_cast<float*>(smraw + 34080);        // [8]
        const float* sa = ia;
        const float* ta = ia + 2048;
        const float* sb = ib;
        const float* tb = ib + 16384;

        for (int i = tid; i < 8192; i += 256) h2L[i] = h2ws[i];
        if (tid < 8) { sA[tid] = 0.f; sB[tid] = 0.f; }
        __syncthreads();
        if (tid < 160) {
            int b = tid / 10, j = tid - b * 10;
            float a = b2[j];
            const float* h = h2L + b * 512;
            for (int c = 0; c < 512; ++c) a += h[c] * W2[c * 10 + j];
            lgL[tid] = a;
        }
        __syncthreads();
        if (tid < 16) {
            int b = tid;
            float mx = lgL[b * 10];
            for (int j = 1; j < 10; ++j) mx = fmaxf(mx, lgL[b * 10 + j]);
            float sum = 0.f, ex[10];
            for (int j = 0; j < 10; ++j) { ex[j] = expf(lgL[b * 10 + j] - mx); sum += ex[j]; }
            for (int j = 0; j < 10; ++j) {
                float p = ex[j] / sum;
                ypL[b * 10 + j] = p;
                dout[b * 10 + j] = p;
            }
        }
        __syncthreads();
        if (tid < 128) {
            int f = tid >> 4, s = tid & 15;
            float d = 0.f;
            for (int b = 0; b < 16; ++b) d += sa[f * 256 + b * 16 + s] - ta[f * 256 + b * 16 + s];
            d *= (1.f / 16.f);
            atomicAdd(&sA[f], d * d);
        }
        for (int e = tid; e < 1024; e += 256) {
            int i = e >> 7, f = (e >> 4) & 7, s = e & 15;
            float d = 0.f;
            int base = ((i * 8 + f) * 16) * 16 + s;
            for (int b = 0; b < 16; ++b) d += sb[base + b * 16] - tb[base + b * 16];
            d *= (1.f / 16.f);
            atomicAdd(&sB[i], d * d);
        }
        __syncthreads();
        if (tid == 0) {
            float la = 0.f, lb = 0.f;
            for (int f = 0; f < 8; ++f) la += sqrtf(sA[f]);
            for (int i = 0; i < 8; ++i) lb += sqrtf(sB[i]);
            la *= 0.1f / 8.f;
            lb *= 0.1f / 8.f;
            float ce = 0.f;
            for (int b = 0; b < 16; ++b) {
                const float* y = ypL + b * 10;
                float mx = y[0];
                for (int j = 1; j < 10; ++j) mx = fmaxf(mx, y[j]);
                float sum = 0.f;
                for (int j = 0; j < 10; ++j) sum += expf(y[j] - mx);
                float lse = mx + logf(sum);
                ce += lse - y[sy[b]];
            }
            ce *= (1.f / 16.f);
            dout[160] = ce + la + lb;
        }
    }
}

extern "C" void kernel_launch(void* const* d_in, const int* in_sizes, int n_in,
                              void* d_out, int out_size, void* d_ws, size_t ws_size,
                              hipStream_t stream) {
    (void)in_sizes; (void)n_in; (void)out_size; (void)ws_size;
    const float* src_x = (const float*)d_in[0];
    const int*   src_y = (const int*)d_in[1];
    const float* tgt_x = (const float*)d_in[2];
    const float *cw1 = (const float*)d_in[3], *bn1g = (const float*)d_in[4],
                *bn1b = (const float*)d_in[5], *bn1m = (const float*)d_in[6],
                *bn1v = (const float*)d_in[7];
    const float *cw2 = (const float*)d_in[8], *bn2g = (const float*)d_in[9],
                *bn2b = (const float*)d_in[10], *bn2m = (const float*)d_in[11],
                *bn2v = (const float*)d_in[12];
    const float *cw3 = (const float*)d_in[13], *bn3g = (const float*)d_in[14],
                *bn3b = (const float*)d_in[15], *bn3m = (const float*)d_in[16],
                *bn3v = (const float*)d_in[17];
    const float *Wq = (const float*)d_in[18], *bq = (const float*)d_in[19],
                *Wk = (const float*)d_in[20], *bk = (const float*)d_in[21],
                *Wv = (const float*)d_in[22], *bv = (const float*)d_in[23];
    const float *bc1g = (const float*)d_in[24], *bc1b = (const float*)d_in[25],
                *bc1m = (const float*)d_in[26], *bc1v = (const float*)d_in[27];
    const float *W1 = (const float*)d_in[28], *b1 = (const float*)d_in[29];
    const float *bc2g = (const float*)d_in[30], *bc2b = (const float*)d_in[31],
                *bc2m = (const float*)d_in[32], *bc2v = (const float*)d_in[33];
    const float *W2 = (const float*)d_in[34], *b2 = (const float*)d_in[35];

    float* ws = (float*)d_ws;
    size_t o = 0;
    float* rep    = ws + o; o += (size_t)2 * 262144;   // [pass][f,n,h]
    float* Zn     = ws + o; o += (size_t)2 * 16384;
    float* rninv  = ws + o; o += (size_t)2 * 2048;
    float* ia     = ws + o; o += (size_t)2 * 2048;
    float* ib     = ws + o; o += (size_t)2 * 16384;
    float* featbn = ws + o; o += (size_t)16 * 2048;
    float* h2ws   = ws + o; o += (size_t)16 * 512;
    u16* wpk2 = (u16*)(ws + o); o += 65536;            // 131072 u16
    u16* wpk3 = (u16*)(ws + o); o += 262144;           // 524288 u16
    u16* wqkv = (u16*)(ws + o); o += 24576;            // 49152 u16

    k_wprep<<<688, 256, 0, stream>>>(cw2, cw3, Wq, Wk, Wv, wpk2, wpk3, wqkv);
    k_cnn<<<4096, 256, 0, stream>>>(src_x, tgt_x,
        cw1, bn1g, bn1b, bn1m, bn1v,
        bn2g, bn2b, bn2m, bn2v,
        bn3g, bn3b, bn3m, bn3v,
        wpk2, wpk3, rep);

    float* dout_f = (float*)d_out;
    void* args[] = {
        (void*)&rep, (void*)&wqkv, (void*)&bq, (void*)&bk, (void*)&bv,
        (void*)&Zn, (void*)&rninv, (void*)&ia, (void*)&ib,
        (void*)&bc1g, (void*)&bc1b, (void*)&bc1m, (void*)&bc1v,
        (void*)&featbn,
        (void*)&W1, (void*)&b1, (void*)&bc2g, (void*)&bc2b, (void*)&bc2m, (void*)&bc2v,
        (void*)&h2ws,
        (void*)&W2, (void*)&b2, (void*)&src_y, (void*)&dout_f };
    hipLaunchCooperativeKernel((const void*)k_post, dim3(256), dim3(256),
                               args, 0, stream);
}

// Round 12
// 294.866 us; speedup vs baseline: 1.4572x; 1.4572x over previous
//
#include <hip/hip_runtime.h>

typedef unsigned short u16;
typedef unsigned int u32;
typedef __attribute__((ext_vector_type(8))) short bfrag;     // 8 bf16
typedef __attribute__((ext_vector_type(4))) float ffrag;     // 4 fp32 acc
typedef __attribute__((ext_vector_type(16))) float ffrag16;  // 16 fp32 acc (32x32)

__device__ __forceinline__ float lrelu(float x) { return x >= 0.f ? x : 0.01f * x; }
__device__ __forceinline__ float eluf(float x)  { return x > 0.f ? x : expm1f(x); }
__device__ __forceinline__ u16 f2bf(float f) {            // RNE (wprep only)
    u32 x = __float_as_uint(f);
    return (u16)((x + 0x7fffu + ((x >> 16) & 1u)) >> 16);
}
__device__ __forceinline__ u16 f2bt(float f) {            // truncate (internal)
    return (u16)(__float_as_uint(f) >> 16);
}
__device__ __forceinline__ float bf2f(u16 u) {
    return __uint_as_float(((u32)u) << 16);
}

// sparsemax over 16 elements (Martins & Astudillo), exact ksup-count semantics
__device__ void sparsemax16(const float* z, float* out) {
    float zs[16];
    for (int i = 0; i < 16; ++i) zs[i] = z[i];
    for (int i = 1; i < 16; ++i) {
        float key = zs[i]; int j = i - 1;
        while (j >= 0 && zs[j] < key) { zs[j + 1] = zs[j]; --j; }
        zs[j + 1] = key;
    }
    float cum[16];
    cum[0] = zs[0];
    for (int i = 1; i < 16; ++i) cum[i] = cum[i - 1] + zs[i];
    int ksup = 0;
    for (int k = 1; k <= 16; ++k)
        if (1.0f + (float)k * zs[k - 1] > cum[k - 1]) ksup++;
    if (ksup < 1) ksup = 1;
    float tau = (cum[ksup - 1] - 1.0f) / (float)ksup;
    for (int i = 0; i < 16; ++i) out[i] = fmaxf(z[i] - tau, 0.0f);
}

// ---- weight pre-pack, SOURCE-COALESCED (R12) -------------------------------
// Iterate source-linear (aligned float4 reads), invert the permutation for
// the destination index, scatter u16 writes. Read traffic 2.8 MB coalesced
// (was ~8x overfetched stride-32B gather on w3). Dest layouts identical to
// R10 (verified by algebraic inversion of the R10 decode):
//   wpk2: dest = f*16384 + (co>>4)*4096 + kc*512 + L*8 + (ci&7),
//         L = ((ci>>3)<<4)|(co&15);  src s = ((f*64+co)*32+ci)*8+kc
//   wpk3: dest = f*131072 + (co>>5)*32768 + kt*512 + L*8 + (ci&7),
//         kt = tap*4+(ci>>4), L = (((ci>>3)&1)<<5)|(co&31);
//         src s = ((f*128+co)*64+ci)*8+tap
//   wqkv: dest = proj*16384 + (n>>4)*2048 + (k>>5)*512 + L*8 + (r&7),
//         r = k&31, L = ((r>>3)<<4)|(n&15);  src s = k*128+n
__global__ __launch_bounds__(256) void k_wprep(
    const float* __restrict__ w2, const float* __restrict__ w3,
    const float* __restrict__ Wq, const float* __restrict__ Wk,
    const float* __restrict__ Wv,
    u16* __restrict__ wpk2, u16* __restrict__ wpk3, u16* __restrict__ wqkv)
{
    int s0 = (blockIdx.x * 256 + threadIdx.x) * 4;
    if (s0 < 131072) {
        float4 v = *reinterpret_cast<const float4*>(w2 + s0);
        float vv[4] = {v.x, v.y, v.z, v.w};
#pragma unroll
        for (int t = 0; t < 4; ++t) {
            int s = s0 + t;
            int kc = s & 7, ci = (s >> 3) & 31, co = (s >> 8) & 63, f = s >> 14;
            int L = ((ci >> 3) << 4) | (co & 15);
            wpk2[f * 16384 + (co >> 4) * 4096 + kc * 512 + L * 8 + (ci & 7)] = f2bf(vv[t]);
        }
    } else if (s0 < 131072 + 524288) {
        int s0b = s0 - 131072;
        float4 v = *reinterpret_cast<const float4*>(w3 + s0b);
        float vv[4] = {v.x, v.y, v.z, v.w};
#pragma unroll
        for (int t = 0; t < 4; ++t) {
            int s = s0b + t;
            int tap = s & 7, ci = (s >> 3) & 63, co = (s >> 9) & 127, f = s >> 16;
            int kt = tap * 4 + (ci >> 4);
            int L = (((ci >> 3) & 1) << 5) | (co & 31);
            wpk3[f * 131072 + (co >> 5) * 32768 + kt * 512 + L * 8 + (ci & 7)] = f2bf(vv[t]);
        }
    } else if (s0 < 131072 + 524288 + 49152) {
        int s0c = s0 - 655360;
        int proj = s0c >> 14, sidx0 = s0c & 16383;
        const float* W = proj == 0 ? Wq : (proj == 1 ? Wk : Wv);
        float4 v = *reinterpret_cast<const float4*>(W + sidx0);
        float vv[4] = {v.x, v.y, v.z, v.w};
#pragma unroll
        for (int t = 0; t < 4; ++t) {
            int s = sidx0 + t;
            int n = s & 127, k = s >> 7;
            int r = k & 31;
            int L = ((r >> 3) << 4) | (n & 15);
            wqkv[proj * 16384 + (n >> 4) * 2048 + (k >> 5) * 512 + L * 8 + (r & 7)] = f2bf(vv[t]);
        }
    }
}

// ===== fused CNN (both passes): conv1 fp32 -> conv2/conv3 bf16 MFMA ==========
// R10-exact (94 us, FETCH 7.4MB, conflicts 2.6M). Unchanged this round.
#define S1T_STRIDE 40
#define S2T_STRIDE 72
#define RB2_STRIDE 68
#define RB3_STRIDE 140
#define RB_OFF 6336
#define SMEM_U16 (RB_OFF + 67 * RB3_STRIDE)

__global__ __launch_bounds__(256, 3) void k_cnn(
    const float* __restrict__ xs, const float* __restrict__ xt,
    const float* __restrict__ w1, const float* __restrict__ g1, const float* __restrict__ b1,
    const float* __restrict__ m1, const float* __restrict__ v1,
    const float* __restrict__ g2, const float* __restrict__ b2,
    const float* __restrict__ m2, const float* __restrict__ v2,
    const float* __restrict__ g3, const float* __restrict__ b3,
    const float* __restrict__ m3, const float* __restrict__ v3,
    const u16* __restrict__ wpk2, const u16* __restrict__ wpk3,
    float* __restrict__ rep)
{
    __shared__ __align__(16) u16 smem[SMEM_U16];
    float* xin = (float*)(smem + RB_OFF);      // 264 floats (region B head)

    int tid = threadIdx.x, blk = blockIdx.x;
    int pass = blk >> 11, f = (blk >> 8) & 7, n = blk & 255;
    int bb = n >> 4, ss = n & 15;
    int lane = tid & 63, w = tid >> 6;
    const float* x = pass ? xt : xs;
    float* rep_p = rep + (size_t)pass * 262144;

    {
        u32* z = (u32*)smem;
        for (int i = tid; i < 80; i += 256) z[i] = 0;          // s1T rows 0..3
        for (int i = tid; i < 360; i += 256) z[2660 + i] = 0;  // s1T rows 133..150
        if (tid < 4) { xin[tid] = 0.f; xin[260 + tid] = 0.f; }
        const float* xr = x + (((size_t)bb * 8 + f) * 16 + ss) * 256;
        for (int i = tid; i < 256; i += 256) xin[i + 4] = xr[i];
    }
    __syncthreads();

    // ---- conv1 fp32 (1->32, 256 -> conv 257 -> pool 129), ushort4 stores ----
    if (tid < 208) {
        int cc = tid & 7, jc = tid >> 3;
        int co0 = cc * 4, j0 = jc * 5;
        float wr[4][8];
        for (int c = 0; c < 4; ++c) {
            const float4* q = reinterpret_cast<const float4*>(w1 + ((size_t)f * 32 + co0 + c) * 8);
            float4 a = q[0], bq = q[1];
            wr[c][0] = a.x; wr[c][1] = a.y; wr[c][2] = a.z; wr[c][3] = a.w;
            wr[c][4] = bq.x; wr[c][5] = bq.y; wr[c][6] = bq.z; wr[c][7] = bq.w;
        }
        int px[10];
        for (int i = 0; i < 10; ++i) {
            int p = 2 * j0 - 1 + i;
            px[i] = p < 0 ? 0 : (p > 256 ? 256 : p);
        }
        float acc[4][10];
        for (int c = 0; c < 4; ++c) for (int i = 0; i < 10; ++i) acc[c][i] = 0.f;
        for (int k = 0; k < 8; ++k) {
            float xv[10];
            for (int i = 0; i < 10; ++i) xv[i] = xin[px[i] + k];
            for (int c = 0; c < 4; ++c)
                for (int i = 0; i < 10; ++i) acc[c][i] += wr[c][k] * xv[i];
        }
        float scv[4], shv[4];
        for (int c = 0; c < 4; ++c) {
            int co = co0 + c;
            scv[c] = g1[f * 32 + co] * rsqrtf(v1[f * 32 + co] + 1e-5f);
            shv[c] = b1[f * 32 + co] - m1[f * 32 + co] * scv[c];
        }
        for (int jj = 0; jj < 5; ++jj) {
            int j = j0 + jj;
            if (j < 129) {
                ushort4 pk;
                {
                    float a0 = fmaxf(acc[0][2*jj] * scv[0] + shv[0], 0.f);
                    float a1 = fmaxf(acc[0][2*jj+1] * scv[0] + shv[0], 0.f);
                    pk.x = f2bt(fmaxf(a0, a1));
                }
                {
                    float a0 = fmaxf(acc[1][2*jj] * scv[1] + shv[1], 0.f);
                    float a1 = fmaxf(acc[1][2*jj+1] * scv[1] + shv[1], 0.f);
                    pk.y = f2bt(fmaxf(a0, a1));
                }
                {
                    float a0 = fmaxf(acc[2][2*jj] * scv[2] + shv[2], 0.f);
                    float a1 = fmaxf(acc[2][2*jj+1] * scv[2] + shv[2], 0.f);
                    pk.z = f2bt(fmaxf(a0, a1));
                }
                {
                    float a0 = fmaxf(acc[3][2*jj] * scv[3] + shv[3], 0.f);
                    float a1 = fmaxf(acc[3][2*jj+1] * scv[3] + shv[3], 0.f);
                    pk.w = f2bt(fmaxf(a0, a1));
                }
                *reinterpret_cast<ushort4*>(&smem[(j + 4) * S1T_STRIDE + co0]) = pk;
            }
        }
    }
    __syncthreads();

    // ---- conv2 MFMA (M=130, N=64, K=256) -> RB2 raw ----
    {
        bfrag B2[2][8];
        {
            const bfrag* gB = reinterpret_cast<const bfrag*>(wpk2);
            int wN = w & 1;
#pragma unroll
            for (int t = 0; t < 2; ++t)
#pragma unroll
                for (int kc = 0; kc < 8; ++kc)
                    B2[t][kc] = gB[(((size_t)f * 4 + (wN * 2 + t)) * 8 + kc) * 64 + lane];
        }
        int wM = w >> 1, wN = w & 1;
        float sc2[2], sh2[2];
        int co2[2];
#pragma unroll
        for (int t = 0; t < 2; ++t) {
            int co = (wN * 2 + t) * 16 + (lane & 15);
            co2[t] = co;
            sc2[t] = g2[f * 64 + co] * rsqrtf(v2[f * 64 + co] + 1e-5f);
            sh2[t] = b2[f * 64 + co] - m2[f * 64 + co] * sc2[t];
        }
        int arow = lane & 15, ci0 = (lane >> 4) << 3;
        int mtlo = wM ? 5 : 0, mthi = wM ? 9 : 5;
        for (int mt = mtlo; mt < mthi; ++mt) {
            ffrag C0 = {0.f, 0.f, 0.f, 0.f}, C1 = {0.f, 0.f, 0.f, 0.f};
            int rb = mt * 16 + arow;
#pragma unroll
            for (int kc = 0; kc < 8; ++kc) {
                bfrag A = *reinterpret_cast<const bfrag*>(&smem[(rb + kc) * S1T_STRIDE + ci0]);
                C0 = __builtin_amdgcn_mfma_f32_16x16x32_bf16(A, B2[0][kc], C0, 0, 0, 0);
                C1 = __builtin_amdgcn_mfma_f32_16x16x32_bf16(A, B2[1][kc], C1, 0, 0, 0);
            }
            int p0 = mt * 16 + ((lane >> 4) << 2);
#pragma unroll
            for (int r = 0; r < 4; ++r) {
                int p = p0 + r;
                if (p < 130) {
                    smem[RB_OFF + p * RB2_STRIDE + co2[0]] = f2bt(fmaxf(C0[r] * sc2[0] + sh2[0], 0.f));
                    smem[RB_OFF + p * RB2_STRIDE + co2[1]] = f2bt(fmaxf(C1[r] * sc2[1] + sh2[1], 0.f));
                }
            }
        }
    }
    __syncthreads();

    // ---- pool conv2 -> s2T (region A) + zero pad rows, u32-vectorized ----
    {
        u32* z = (u32*)smem;
        for (int i = tid; i < 144; i += 256) z[i] = 0;
        for (int i = tid; i < 612; i += 256) z[2520 + i] = 0;
    }
    {
        const u32* rb2 = reinterpret_cast<const u32*>(smem + RB_OFF);  // stride 34
        u32* s2 = reinterpret_cast<u32*>(smem);                        // stride 36
        for (int e = tid; e < 66 * 32; e += 256) {
            int j = e >> 5, c2 = e & 31;
            u32 v;
            if (j == 0) {
                v = rb2[c2];
            } else if (j == 65) {
                v = rb2[129 * 34 + c2];
            } else {
                u32 a = rb2[(2 * j - 1) * 34 + c2];
                u32 b = rb2[(2 * j) * 34 + c2];
                float a0 = bf2f((u16)a), a1 = bf2f((u16)(a >> 16));
                float b0 = bf2f((u16)b), b1 = bf2f((u16)(b >> 16));
                u16 m0 = a0 > b0 ? (u16)a : (u16)b;
                u16 m1 = a1 > b1 ? (u16)(a >> 16) : (u16)(b >> 16);
                v = (u32)m0 | ((u32)m1 << 16);
            }
            s2[(j + 4) * 36 + c2] = v;
        }
    }
    __syncthreads();

    // ---- conv3 MFMA 32x32x16, kt-outer: 1 B-load + 3 A-reads + 3 MFMA/step --
    {
        int am = lane & 31, hk = (lane >> 5) << 3;
        const bfrag* gB3 = reinterpret_cast<const bfrag*>(wpk3);
        size_t bbase = (((size_t)f * 4 + w) * 32) * 64 + lane;
        ffrag16 C0 = {0.f,0.f,0.f,0.f,0.f,0.f,0.f,0.f,0.f,0.f,0.f,0.f,0.f,0.f,0.f,0.f};
        ffrag16 C1 = {0.f,0.f,0.f,0.f,0.f,0.f,0.f,0.f,0.f,0.f,0.f,0.f,0.f,0.f,0.f,0.f};
        ffrag16 C2 = {0.f,0.f,0.f,0.f,0.f,0.f,0.f,0.f,0.f,0.f,0.f,0.f,0.f,0.f,0.f,0.f};
#pragma unroll 4
        for (int kt = 0; kt < 32; ++kt) {
            int row0 = am + (kt >> 2);
            int ci0 = (kt & 3) * 16 + hk;
            bfrag B = gB3[bbase + (size_t)kt * 64];
            bfrag A0 = *reinterpret_cast<const bfrag*>(&smem[row0 * S2T_STRIDE + ci0]);
            bfrag A1 = *reinterpret_cast<const bfrag*>(&smem[(row0 + 32) * S2T_STRIDE + ci0]);
            bfrag A2 = *reinterpret_cast<const bfrag*>(&smem[(row0 + 64) * S2T_STRIDE + ci0]);
            C0 = __builtin_amdgcn_mfma_f32_32x32x16_bf16(A0, B, C0, 0, 0, 0);
            C1 = __builtin_amdgcn_mfma_f32_32x32x16_bf16(A1, B, C1, 0, 0, 0);
            C2 = __builtin_amdgcn_mfma_f32_32x32x16_bf16(A2, B, C2, 0, 0, 0);
        }
        int ncol = w * 32 + am;
        float sc = g3[f * 128 + ncol] * rsqrtf(v3[f * 128 + ncol] + 1e-5f);
        float sh = b3[f * 128 + ncol] - m3[f * 128 + ncol] * sc;
        int prow_off = (lane >> 5) << 2;
#pragma unroll
        for (int reg = 0; reg < 16; ++reg) {
            int pr = (reg & 3) + 8 * (reg >> 2) + prow_off;
            smem[RB_OFF + pr * RB3_STRIDE + ncol] = f2bt(fmaxf(C0[reg] * sc + sh, 0.f));
            smem[RB_OFF + (32 + pr) * RB3_STRIDE + ncol] = f2bt(fmaxf(C1[reg] * sc + sh, 0.f));
            int p2 = 64 + pr;
            if (p2 < 67)
                smem[RB_OFF + p2 * RB3_STRIDE + ncol] = f2bt(fmaxf(C2[reg] * sc + sh, 0.f));
        }
    }
    __syncthreads();

    // ---- pool conv3 + mean -> rep ----
    if (tid < 128) {
        int co = tid;
        float sum = bf2f(smem[RB_OFF + 0 * RB3_STRIDE + co]);
        for (int j = 1; j < 34; ++j) {
            float a0 = bf2f(smem[RB_OFF + (2 * j - 1) * RB3_STRIDE + co]);
            float a1 = bf2f(smem[RB_OFF + (2 * j) * RB3_STRIDE + co]);
            sum += fmaxf(a0, a1);
        }
        rep_p[(((size_t)f * 256) + n) * 128 + co] = sum * (1.0f / 34.0f);
    }
}

// ---- attn1 (MFMA): QKV proj + Km + scores + sparsemax + Z + rninv ----------
__global__ __launch_bounds__(256) void k_attn1(
    const float* __restrict__ rep, const u16* __restrict__ wqkv,
    const float* __restrict__ bq, const float* __restrict__ bk,
    const float* __restrict__ bv,
    float* __restrict__ Zn, float* __restrict__ rninv, float* __restrict__ iaw)
{
    __shared__ __align__(16) u16 repbf[16 * 136];
    __shared__ float KmL[128], ZL[128], awL[16], scoresL[16], r2L[16];
    __shared__ float spart[4][4][4];
    __shared__ float redL[4];
    int tid = threadIdx.x;
    int pass = blockIdx.x >> 7, f = (blockIdx.x >> 4) & 7, b = blockIdx.x & 15;
    const float* rp = rep + (size_t)pass * 262144 + ((size_t)f * 256 + b * 16) * 128;
    float* Zn_p = Zn + (size_t)pass * 16384;
    float* rninv_p = rninv + (size_t)pass * 2048;
    float* iaw_p = iaw + (size_t)pass * 2048;

    {
        int s = tid >> 4, i = tid & 15, h0 = i * 8;
        const float4* q4 = reinterpret_cast<const float4*>(rp + s * 128 + h0);
        float4 a = q4[0], c = q4[1];
        float p2 = a.x*a.x + a.y*a.y + a.z*a.z + a.w*a.w
                 + c.x*c.x + c.y*c.y + c.z*c.z + c.w*c.w;
        bfrag pk;
        pk[0] = (short)f2bt(a.x); pk[1] = (short)f2bt(a.y);
        pk[2] = (short)f2bt(a.z); pk[3] = (short)f2bt(a.w);
        pk[4] = (short)f2bt(c.x); pk[5] = (short)f2bt(c.y);
        pk[6] = (short)f2bt(c.z); pk[7] = (short)f2bt(c.w);
        *reinterpret_cast<bfrag*>(&repbf[s * 136 + h0]) = pk;
        p2 += __shfl_xor(p2, 1); p2 += __shfl_xor(p2, 2);
        p2 += __shfl_xor(p2, 4); p2 += __shfl_xor(p2, 8);
        if (i == 0) r2L[s] = p2;
    }
    __syncthreads();

    int lane = tid & 63, w = tid >> 6, arow = lane & 15, q = lane >> 4;
    bfrag A[4];
    for (int kc = 0; kc < 4; ++kc)
        A[kc] = *reinterpret_cast<const bfrag*>(&repbf[arow * 136 + kc * 32 + q * 8]);

    float qv[2][4], vvv[2][4];
    int colv[2];
    const bfrag* BB = reinterpret_cast<const bfrag*>(wqkv);
    for (int t = 0; t < 2; ++t) {
        int nt = w * 2 + t;
        ffrag cq = {0.f,0.f,0.f,0.f}, ck = {0.f,0.f,0.f,0.f}, cv = {0.f,0.f,0.f,0.f};
        for (int kc = 0; kc < 4; ++kc) {
            int fi = (nt * 4 + kc) * 64 + lane;
            bfrag Bq = BB[fi];
            bfrag Bk = BB[2048 + fi];
            bfrag Bv = BB[4096 + fi];
            cq = __builtin_amdgcn_mfma_f32_16x16x32_bf16(A[kc], Bq, cq, 0, 0, 0);
            ck = __builtin_amdgcn_mfma_f32_16x16x32_bf16(A[kc], Bk, ck, 0, 0, 0);
            cv = __builtin_amdgcn_mfma_f32_16x16x32_bf16(A[kc], Bv, cv, 0, 0, 0);
        }
        int col = nt * 16 + arow;
        colv[t] = col;
        float bqc = bq[col], bkc = bk[col], bvc = bv[col];
        float kpt = 0.f;
        for (int r = 0; r < 4; ++r) {
            qv[t][r] = eluf(cq[r] + bqc);
            vvv[t][r] = lrelu(cv[r] + bvc);
            kpt += lrelu(ck[r] + bkc);
        }
        kpt += __shfl_xor(kpt, 16);
        kpt += __shfl_xor(kpt, 32);
        if (q == 0) KmL[col] = kpt * (1.f / 16.f);
    }
    __syncthreads();

    {
        float km0 = KmL[colv[0]], km1 = KmL[colv[1]];
        float ps[4];
        for (int r = 0; r < 4; ++r) {
            float v = qv[0][r] * km0 + qv[1][r] * km1;
            v += __shfl_xor(v, 1); v += __shfl_xor(v, 2);
            v += __shfl_xor(v, 4); v += __shfl_xor(v, 8);
            ps[r] = v;
        }
        if (arow == 0)
            for (int r = 0; r < 4; ++r) spart[w][q][r] = ps[r];
    }
    __syncthreads();
    if (tid < 16) {
        int qq = tid >> 2, rr = tid & 3;
        float sc = spart[0][qq][rr] + spart[1][qq][rr] + spart[2][qq][rr] + spart[3][qq][rr];
        scoresL[tid] = sc * 0.08838834764831845f;   // 1/sqrt(128)
        rninv_p[f * 256 + b * 16 + tid] = 1.f / fmaxf(sqrtf(r2L[tid]), 1e-12f);
    }
    __syncthreads();
    if (tid == 0) sparsemax16(scoresL, awL);
    __syncthreads();
    if (tid < 16) iaw_p[f * 256 + b * 16 + tid] = awL[tid];

    for (int t = 0; t < 2; ++t) {
        float zp = 0.f;
        for (int r = 0; r < 4; ++r) zp += awL[q * 4 + r] * vvv[t][r];
        zp += __shfl_xor(zp, 16);
        zp += __shfl_xor(zp, 32);
        if (q == 0) ZL[colv[t]] = zp;
    }
    __syncthreads();
    if (tid < 128) {
        float z = ZL[tid];
        float v = z * z;
        v += __shfl_xor(v, 1); v += __shfl_xor(v, 2); v += __shfl_xor(v, 4);
        v += __shfl_xor(v, 8); v += __shfl_xor(v, 16); v += __shfl_xor(v, 32);
        if (lane == 0) redL[w] = v;
    }
    __syncthreads();
    if (tid == 0) redL[2] = 1.f / fmaxf(sqrtf(redL[0] + redL[1]), 1e-12f);
    __syncthreads();
    if (tid < 128)
        Zn_p[((size_t)f * 16 + b) * 128 + tid] = ZL[tid] * redL[2];
}

// ---- attn2 (split): one block per (pass,b,i) -------------------------------
__global__ __launch_bounds__(256) void k_attn2(
    const float* __restrict__ rep, const float* __restrict__ Zn,
    const float* __restrict__ rninv, float* __restrict__ ibw,
    const float* __restrict__ g, const float* __restrict__ bb,
    const float* __restrict__ mm, const float* __restrict__ vv,
    float* __restrict__ featbn)
{
    __shared__ float repL[16384];    // [f][s][h]
    __shared__ float ZiL[128], scores[128], UL[128];
    __shared__ float awLf[8][16];
    __shared__ float redL[2];
    int tid = threadIdx.x, blk = blockIdx.x;
    int pass = blk >> 7, b = (blk >> 3) & 15, i = blk & 7;
    const float* rep_p = rep + (size_t)pass * 262144;

    for (int f = 0; f < 8; ++f) {
        const float4* src = reinterpret_cast<const float4*>(
            rep_p + ((size_t)f * 256 + b * 16) * 128);
        float4* dst = reinterpret_cast<float4*>(repL + f * 2048);
        for (int t = tid; t < 512; t += 256) dst[t] = src[t];
    }
    if (tid < 128) ZiL[tid] = Zn[(size_t)pass * 16384 + ((size_t)i * 16 + b) * 128 + tid];
    __syncthreads();

    if (tid < 128) {
        int f = tid >> 4, s = tid & 15;
        const float* rr = repL + tid * 128;
        float a = 0.f;
        for (int h = 0; h < 128; ++h) a += ZiL[h] * rr[h];
        scores[tid] = a * rninv[(size_t)pass * 2048 + f * 256 + b * 16 + s];
    }
    __syncthreads();
    if (tid < 8) {
        float aw[16];
        sparsemax16(&scores[tid * 16], aw);
        for (int s = 0; s < 16; ++s) awLf[tid][s] = aw[s];
    }
    __syncthreads();
    if (tid < 128) {
        int f = tid >> 4, s = tid & 15;
        ibw[(size_t)pass * 16384 + (((size_t)i * 8 + f) * 16 + b) * 16 + s] = awLf[f][s];
    }
    if (pass == 0) {
        if (tid < 128) {
            int h = tid;
            float u = 0.f;
            for (int f = 0; f < 8; ++f) {
                const float* rr = repL + f * 2048 + h;
                const float* aa = awLf[f];
                for (int s = 0; s < 16; ++s) u += aa[s] * rr[s * 128];
            }
            UL[h] = u * 0.125f;
        }
        __syncthreads();
        if (tid < 128) {
            int lane = tid & 63, w = tid >> 6;
            float v = ZiL[tid] * ZiL[tid] + UL[tid] * UL[tid];
            v += __shfl_xor(v, 1); v += __shfl_xor(v, 2); v += __shfl_xor(v, 4);
            v += __shfl_xor(v, 8); v += __shfl_xor(v, 16); v += __shfl_xor(v, 32);
            if (lane == 0) redL[w] = v;
        }
        __syncthreads();
        if (tid < 256) {
            float inv = 1.f / fmaxf(sqrtf(redL[0] + redL[1]), 1e-12f);
            int d = tid;
            int e = i * 256 + d;
            float val = (d < 128 ? ZiL[d] : UL[d - 128]) * inv;
            float scv = g[e] * rsqrtf(vv[e] + 1e-5f);
            featbn[b * 2048 + e] = (val - mm[e]) * scv + bb[e];
        }
    }
}

// ---- head stage 1 (vectorized): bn(feat)@W1+b1 -> bn2 -> lrelu -------------
__global__ __launch_bounds__(256) void k_head1(
    const float* __restrict__ featbn,
    const float* __restrict__ W1, const float* __restrict__ b1,
    const float* __restrict__ g2, const float* __restrict__ bb2,
    const float* __restrict__ mm2, const float* __restrict__ vv2,
    float* __restrict__ h2ws)
{
    __shared__ float featL[2048];
    __shared__ float part[32][32];
    int tid = threadIdx.x, blk = blockIdx.x;
    int b = blk >> 4, cc = blk & 15;
    {
        const float4* src = reinterpret_cast<const float4*>(featbn + b * 2048);
        float4* dst = reinterpret_cast<float4*>(featL);
        for (int i = tid; i < 512; i += 256) dst[i] = src[i];
    }
    __syncthreads();
    int ks = tid >> 3, cg = tid & 7;
    int col0 = cc * 32 + cg * 4;
    float4 acc = {0.f, 0.f, 0.f, 0.f};
    const float* fl = featL + ks * 64;
    for (int c = 0; c < 64; ++c) {
        int k = ks * 64 + c;
        float4 wv = *reinterpret_cast<const float4*>(W1 + (size_t)k * 512 + col0);
        float fv = fl[c];
        acc.x += fv * wv.x; acc.y += fv * wv.y;
        acc.z += fv * wv.z; acc.w += fv * wv.w;
    }
    part[ks][cg * 4 + 0] = acc.x;
    part[ks][cg * 4 + 1] = acc.y;
    part[ks][cg * 4 + 2] = acc.z;
    part[ks][cg * 4 + 3] = acc.w;
    __syncthreads();
    if (tid < 32) {
        int colw = cc * 32 + tid;
        float s = b1[colw];
        for (int k2 = 0; k2 < 32; ++k2) s += part[k2][tid];
        float scv = g2[colw] * rsqrtf(vv2[colw] + 1e-5f);
        float val = (s - mm2[colw]) * scv + bb2[colw];
        h2ws[b * 512 + colw] = lrelu(val);
    }
}

// ---- tail: h2 @ W2 + b2, softmax -> dout[0:160]; MMD + CE -> dout[160] -----
__global__ __launch_bounds__(256) void k_tail(
    const float* __restrict__ h2ws,
    const float* __restrict__ W2, const float* __restrict__ b2,
    const float* __restrict__ sa, const float* __restrict__ ta,
    const float* __restrict__ sb, const float* __restrict__ tb,
    const int* __restrict__ sy, float* __restrict__ dout)
{
    __shared__ float h2L[8192];
    __shared__ float lgL[160], ypL[160];
    __shared__ float sA[8], sB[8];
    int tid = threadIdx.x;
    for (int i = tid; i < 8192; i += 256) h2L[i] = h2ws[i];
    if (tid < 8) { sA[tid] = 0.f; sB[tid] = 0.f; }
    __syncthreads();
    if (tid < 160) {
        int b = tid / 10, j = tid - b * 10;
        float a = b2[j];
        const float* h = h2L + b * 512;
        for (int c = 0; c < 512; ++c) a += h[c] * W2[c * 10 + j];
        lgL[tid] = a;
    }
    __syncthreads();
    if (tid < 16) {
        int b = tid;
        float mx = lgL[b * 10];
        for (int j = 1; j < 10; ++j) mx = fmaxf(mx, lgL[b * 10 + j]);
        float sum = 0.f, ex[10];
        for (int j = 0; j < 10; ++j) { ex[j] = expf(lgL[b * 10 + j] - mx); sum += ex[j]; }
        for (int j = 0; j < 10; ++j) {
            float p = ex[j] / sum;
            ypL[b * 10 + j] = p;
            dout[b * 10 + j] = p;
        }
    }
    __syncthreads();
    if (tid < 128) {
        int f = tid >> 4, s = tid & 15;
        float d = 0.f;
        for (int b = 0; b < 16; ++b) d += sa[f * 256 + b * 16 + s] - ta[f * 256 + b * 16 + s];
        d *= (1.f / 16.f);
        atomicAdd(&sA[f], d * d);
    }
    for (int e = tid; e < 1024; e += 256) {
        int i = e >> 7, f = (e >> 4) & 7, s = e & 15;
        float d = 0.f;
        int base = ((i * 8 + f) * 16) * 16 + s;
        for (int b = 0; b < 16; ++b) d += sb[base + b * 16] - tb[base + b * 16];
        d *= (1.f / 16.f);
        atomicAdd(&sB[i], d * d);
    }
    __syncthreads();
    if (tid == 0) {
        float la = 0.f, lb = 0.f;
        for (int f = 0; f < 8; ++f) la += sqrtf(sA[f]);
        for (int i = 0; i < 8; ++i) lb += sqrtf(sB[i]);
        la *= 0.1f / 8.f;
        lb *= 0.1f / 8.f;
        float ce = 0.f;
        for (int b = 0; b < 16; ++b) {
            const float* y = ypL + b * 10;
            float mx = y[0];
            for (int j = 1; j < 10; ++j) mx = fmaxf(mx, y[j]);
            float sum = 0.f;
            for (int j = 0; j < 10; ++j) sum += expf(y[j] - mx);
            float lse = mx + logf(sum);
            ce += lse - y[sy[b]];
        }
        ce *= (1.f / 16.f);
        dout[160] = ce + la + lb;
    }
}

extern "C" void kernel_launch(void* const* d_in, const int* in_sizes, int n_in,
                              void* d_out, int out_size, void* d_ws, size_t ws_size,
                              hipStream_t stream) {
    (void)in_sizes; (void)n_in; (void)out_size; (void)ws_size;
    const float* src_x = (const float*)d_in[0];
    const int*   src_y = (const int*)d_in[1];
    const float* tgt_x = (const float*)d_in[2];
    const float *cw1 = (const float*)d_in[3], *bn1g = (const float*)d_in[4],
                *bn1b = (const float*)d_in[5], *bn1m = (const float*)d_in[6],
                *bn1v = (const float*)d_in[7];
    const float *cw2 = (const float*)d_in[8], *bn2g = (const float*)d_in[9],
                *bn2b = (const float*)d_in[10], *bn2m = (const float*)d_in[11],
                *bn2v = (const float*)d_in[12];
    const float *cw3 = (const float*)d_in[13], *bn3g = (const float*)d_in[14],
                *bn3b = (const float*)d_in[15], *bn3m = (const float*)d_in[16],
                *bn3v = (const float*)d_in[17];
    const float *Wq = (const float*)d_in[18], *bq = (const float*)d_in[19],
                *Wk = (const float*)d_in[20], *bk = (const float*)d_in[21],
                *Wv = (const float*)d_in[22], *bv = (const float*)d_in[23];
    const float *bc1g = (const float*)d_in[24], *bc1b = (const float*)d_in[25],
                *bc1m = (const float*)d_in[26], *bc1v = (const float*)d_in[27];
    const float *W1 = (const float*)d_in[28], *b1 = (const float*)d_in[29];
    const float *bc2g = (const float*)d_in[30], *bc2b = (const float*)d_in[31],
                *bc2m = (const float*)d_in[32], *bc2v = (const float*)d_in[33];
    const float *W2 = (const float*)d_in[34], *b2 = (const float*)d_in[35];

    float* ws = (float*)d_ws;
    size_t o = 0;
    float* rep    = ws + o; o += (size_t)2 * 262144;   // [pass][f,n,h]
    float* Zn     = ws + o; o += (size_t)2 * 16384;
    float* rninv  = ws + o; o += (size_t)2 * 2048;
    float* ia     = ws + o; o += (size_t)2 * 2048;
    float* ib     = ws + o; o += (size_t)2 * 16384;
    float* featbn = ws + o; o += (size_t)16 * 2048;
    float* h2ws   = ws + o; o += (size_t)16 * 512;
    u16* wpk2 = (u16*)(ws + o); o += 65536;            // 131072 u16
    u16* wpk3 = (u16*)(ws + o); o += 262144;           // 524288 u16
    u16* wqkv = (u16*)(ws + o); o += 24576;            // 49152 u16

    k_wprep<<<688, 256, 0, stream>>>(cw2, cw3, Wq, Wk, Wv, wpk2, wpk3, wqkv);
    k_cnn<<<4096, 256, 0, stream>>>(src_x, tgt_x,
        cw1, bn1g, bn1b, bn1m, bn1v,
        bn2g, bn2b, bn2m, bn2v,
        bn3g, bn3b, bn3m, bn3v,
        wpk2, wpk3, rep);
    k_attn1<<<256, 256, 0, stream>>>(rep, wqkv, bq, bk, bv, Zn, rninv, ia);
    k_attn2<<<256, 256, 0, stream>>>(rep, Zn, rninv, ib, bc1g, bc1b, bc1m, bc1v, featbn);
    k_head1<<<256, 256, 0, stream>>>(featbn, W1, b1, bc2g, bc2b, bc2m, bc2v, h2ws);
    k_tail<<<1, 256, 0, stream>>>(h2ws, W2, b2, ia, ia + 2048, ib, ib + 16384,
                                  src_y, (float*)d_out);
}